// Round 7
// baseline (13.992 us; speedup 1.0000x reference)
//
#include <hip/hip_runtime.h>
#include <hip/hip_bf16.h>

#define CC 16     // hidden states
#define MM 32     // label alphabet
#define NGEN 16   // generators
#define TLP 17    // padded LDS stride for T table
#define GPB 8     // graphs per block (one per wave, 512 threads)

// Single fused kernel; each 512-thread block owns 8 graphs (one per wave).
//  (0) issue B/Pi global loads into registers (in flight during search)
//  (1) per-wave dual 32-ary ballot lower_bound on sorted batch -> [start,end)
//  (2) stage B->LDS; block-redundant 32x16 table T[m][g] via
//      log(num) = Pi + B - log dPi - log dB  (few logf, mostly FMA)
//  (3) per-wave exact 32-bin label histogram: coalesced 64-node iterations,
//      integer LDS atomics (order-independent -> deterministic)
//  (4) out[g] = -sum_m cnt[m]*T[m][g]  (same arithmetic order as R6)
__global__ void __launch_bounds__(512) cgmm_fused_kernel(
        const int* __restrict__ x,
        const int* __restrict__ batch,
        const float* __restrict__ B,
        const float* __restrict__ Pi,
        float* __restrict__ out,
        int n_nodes, int n_graphs) {
    __shared__ float Bs[CC * MM * NGEN];   // 32 KB raw B
    __shared__ float ePiS[CC * NGEN];
    __shared__ float dPiS[NGEN];
    __shared__ float Acg[CC * NGEN];       // ePi/(dPi*dB)
    __shared__ float Lcg[CC * NGEN];       // Pi - log dPi - log dB
    __shared__ float Tl[MM * TLP];
    __shared__ int   hist[GPB][MM];

    const int tid  = threadIdx.x;
    const int wave = tid >> 6;
    const int lane = tid & 63;
    const int gid  = blockIdx.x * GPB + wave;

    // ---- (0) early global loads (stay in VGPRs through the search) ----
    const float4* B4 = (const float4*)B;
    float4 breg[4];
    #pragma unroll
    for (int i = 0; i < 4; ++i) breg[i] = B4[tid + i * 512];
    const float pireg = (tid < CC * NGEN) ? Pi[tid] : 0.f;
    if (lane < MM) hist[wave][lane] = 0;

    // ---- (1) per-wave boundary search (lanes 0-31: start, 32-63: end) ----
    int start = 0, end = 0;
    if (gid < n_graphs) {
        const int half = lane >> 5;
        const int li   = lane & 31;
        const int target = gid + half;

        int lo = 0, hi = n_nodes;
        while (hi - lo > 32) {
            const int step = (hi - lo) >> 5;           // >= 1
            const int p = lo + li * step;
            const bool c = batch[p] < target;
            const unsigned mask = (unsigned)(__ballot(c) >> (half << 5));
            const int k = __popc(mask);                // monotone prefix
            if (k == 0) {
                hi = lo;
            } else {
                const int nhi = (k < 32) ? (lo + k * step) : hi;
                lo = lo + (k - 1) * step + 1;
                hi = nhi;
            }
        }
        int bound;
        {
            const int p = lo + li;
            const bool c = (p < hi) && (batch[p] < target);
            const unsigned mask = (unsigned)(__ballot(c) >> (half << 5));
            bound = lo + __popc(mask);
        }
        start = __shfl(bound, 0);
        end   = __shfl(bound, 32);
    }

    // ---- (2) stage LDS, compute table ----
    {
        float4* Bs4 = (float4*)Bs;
        #pragma unroll
        for (int i = 0; i < 4; ++i) Bs4[tid + i * 512] = breg[i];
        if (tid < CC * NGEN) ePiS[tid] = expf(pireg);
    }
    __syncthreads();

    float dB = 0.f;
    if (tid < CC * NGEN) {
        const int c = tid >> 4, g = tid & 15;
        #pragma unroll
        for (int m = 0; m < MM; ++m)
            dB += expf(Bs[(c * MM + m) * NGEN + g]);
    } else if (tid < CC * NGEN + NGEN) {
        const int gg = tid - CC * NGEN;
        float s = 0.f;
        #pragma unroll
        for (int cc = 0; cc < CC; ++cc) s += ePiS[cc * NGEN + gg];
        dPiS[gg] = s;
    }
    __syncthreads();
    if (tid < CC * NGEN) {
        const int g = tid & 15;
        Acg[tid] = ePiS[tid] / (dPiS[g] * dB);
        Lcg[tid] = pireg - logf(dPiS[g]) - logf(dB);
    }
    __syncthreads();
    {
        const int m = tid >> 4;                        // 0..31
        const int g = tid & 15;                        // 0..15
        float ssum = 0.f, lsum = 0.f;
        #pragma unroll
        for (int cc = 0; cc < CC; ++cc) {
            const float b  = Bs[(cc * MM + m) * NGEN + g];
            const float ne = Acg[cc * NGEN + g] * expf(b);
            ssum += ne;
            lsum += ne * (Lcg[cc * NGEN + g] + b);
        }
        Tl[m * TLP + g] = lsum / ssum;
    }
    __syncthreads();

    // ---- (3) per-wave histogram: coalesced, integer LDS atomics ----
    if (gid < n_graphs) {
        for (int n = start + lane; n < end; n += 64)
            atomicAdd(&hist[wave][x[n]], 1);

        // per-wave LDS ops complete in issue order -> no block sync needed
        // ---- (4) combine: lane = g + 16*q, q owns 8 m's ----
        const int g = lane & 15;
        const int q = lane >> 4;                       // 0..3
        float acc = 0.f;
        #pragma unroll
        for (int j = 0; j < 8; ++j) {
            const int m = q * 8 + j;
            acc += (float)hist[wave][m] * Tl[m * TLP + g];
        }
        acc += __shfl_down(acc, 32);
        acc += __shfl_down(acc, 16);
        if (lane < NGEN) out[gid * NGEN + lane] = -acc;
    }
}

extern "C" void kernel_launch(void* const* d_in, const int* in_sizes, int n_in,
                              void* d_out, int out_size, void* d_ws, size_t ws_size,
                              hipStream_t stream) {
    const int* x     = (const int*)d_in[0];
    // d_in[1] = edge_index : unused by layer 0 (never read)
    const int* batch = (const int*)d_in[2];
    const float* B   = (const float*)d_in[3];
    const float* Pi  = (const float*)d_in[4];
    float* out       = (float*)d_out;

    const int n_nodes  = in_sizes[0];
    const int n_graphs = out_size / NGEN;

    hipLaunchKernelGGL(cgmm_fused_kernel,
                       dim3((n_graphs + GPB - 1) / GPB), dim3(512), 0, stream,
                       x, batch, B, Pi, out, n_nodes, n_graphs);
}

// Round 8
// 12.601 us; speedup vs baseline: 1.1104x; 1.1104x over previous
//
#include <hip/hip_runtime.h>
#include <hip/hip_bf16.h>

#define CC 16     // hidden states
#define MM 32     // label alphabet
#define NGEN 16   // generators
#define TLP 17    // padded LDS stride for T table
#define GPB 8     // graphs per block in K2 (one per wave)

// K1: Block 0 computes the 32x16 table T:
//   T[m][g] = sum_c (num[c]/s)*log(num[c]), num[c] = smPi[c][g]*smB[c][m][g]
// via log(num[c]) = Pi[c][g] + B[c][m][g] - log dPi[g] - log dB[c][g]
// (272 logf total). Blocks 1.. scan sorted batch and write per-graph node
// ranges r[2*gph] = start, r[2*gph+1] = end (each element exactly once).
__global__ void __launch_bounds__(256) cgmm_prep_kernel(
        const float* __restrict__ B,
        const float* __restrict__ Pi,
        const int* __restrict__ batch,
        float* __restrict__ T,
        int* __restrict__ r,          // 2*n_graphs ints: (start,end) pairs
        int n_nodes, int n_graphs) {
    if (blockIdx.x == 0) {
        __shared__ float E[CC][MM][NGEN];   // exp(B), 32 KB
        __shared__ float Acg[CC][NGEN];     // ePi/(dPi*dB)
        __shared__ float Lcg[CC][NGEN];     // Pi - log dPi - log dB
        __shared__ float ePi[CC][NGEN];
        __shared__ float dPi[NGEN];

        const int tid = threadIdx.x;        // 0..255
        const int c = tid >> 4, g = tid & 15;

        float s = 0.f;
        #pragma unroll
        for (int m = 0; m < MM; ++m) {
            const float e = expf(B[(c * MM + m) * NGEN + g]);
            E[c][m][g] = e;
            s += e;
        }
        const float dB = s;
        ePi[c][g] = expf(Pi[c * NGEN + g]);
        __syncthreads();
        if (tid < NGEN) {
            float t = 0.f;
            #pragma unroll
            for (int cc = 0; cc < CC; ++cc) t += ePi[cc][tid];
            dPi[tid] = t;
        }
        __syncthreads();
        Acg[c][g] = ePi[c][g] / (dPi[g] * dB);
        Lcg[c][g] = Pi[c * NGEN + g] - logf(dPi[g]) - logf(dB);
        __syncthreads();

        #pragma unroll
        for (int rr = 0; rr < 2; ++rr) {
            const int m = (tid >> 4) + rr * 16;
            float ssum = 0.f, lsum = 0.f;
            #pragma unroll
            for (int cc = 0; cc < CC; ++cc) {
                const float ne = Acg[cc][g] * E[cc][m][g];
                ssum += ne;
                lsum += ne * (Lcg[cc][g] + B[(cc * MM + m) * NGEN + g]);
            }
            T[m * NGEN + g] = lsum / ssum;
        }
    } else {
        // boundary scan: logical offs[gph] = first n with batch[n] >= gph;
        // emit as pairs: offs[g] -> r[2g] (start of g) and r[2g-1] (end of g-1)
        const int idx = (blockIdx.x - 1) * blockDim.x + threadIdx.x;
        const int stride = (gridDim.x - 1) * blockDim.x;
        for (int n = idx; n < n_nodes; n += stride) {
            const int b = batch[n];
            const int prev = (n == 0) ? -1 : batch[n - 1];
            for (int gph = prev + 1; gph <= b; ++gph) {
                if (gph < n_graphs) r[2 * gph] = n;
                if (gph > 0)        r[2 * gph - 1] = n;
            }
            if (n == n_nodes - 1) {
                for (int gph = b + 1; gph <= n_graphs; ++gph) {
                    if (gph < n_graphs) r[2 * gph] = n_nodes;
                    if (gph > 0)        r[2 * gph - 1] = n_nodes;
                }
            }
        }
    }
}

// K2: 8 graphs per 512-thread block, one per wave. Per wave: one aligned int2
// range load, then an exact 32-bin label histogram with fully-coalesced
// 64-node iterations (integer LDS atomics -> order-independent ->
// deterministic), software-pipelined so the next 64 x-loads are in flight
// under the current ds_adds. Combine out[g] = -sum_m cnt[m]*T[m][g].
__global__ void __launch_bounds__(512) cgmm_graph_kernel(
        const int* __restrict__ x,
        const int* __restrict__ ranges,   // int2 pairs
        const float* __restrict__ T,
        float* __restrict__ out,
        int n_graphs) {
    __shared__ float Tl[MM * TLP];
    __shared__ int hist[GPB][MM];

    const int tid  = threadIdx.x;
    const int wave = tid >> 6;
    const int lane = tid & 63;
    const int gid  = blockIdx.x * GPB + wave;

    if (tid < MM * NGEN)
        Tl[(tid >> 4) * TLP + (tid & 15)] = T[tid];   // in flight early
    if (lane < MM)
        hist[wave][lane] = 0;

    int start = 0, end = 0;
    if (gid < n_graphs) {
        const int2 se = *(const int2*)(ranges + 2 * gid);  // 8B aligned
        start = se.x;
        end   = se.y;
    }

    // software-pipelined coalesced histogram (per-wave LDS ops are in-order)
    int n  = start + lane;
    int xv = (n < end) ? x[n] : -1;
    for (int base = start; base < end; base += 64) {
        const int nn = base + 64 + lane;
        const int xn = (nn < end) ? x[nn] : -1;   // prefetch next round
        if (xv >= 0) atomicAdd(&hist[wave][xv], 1);
        xv = xn;
    }

    __syncthreads();   // Tl staged across waves; hist ds_adds complete

    if (gid < n_graphs) {
        const int g = lane & 15;
        const int q = lane >> 4;          // 0..3, owns m = q*8 .. q*8+7
        float acc = 0.f;
        #pragma unroll
        for (int j = 0; j < 8; ++j) {
            const int m = q * 8 + j;
            acc += (float)hist[wave][m] * Tl[m * TLP + g];
        }
        acc += __shfl_down(acc, 32);
        acc += __shfl_down(acc, 16);
        if (lane < NGEN) out[gid * NGEN + lane] = -acc;
    }
}

extern "C" void kernel_launch(void* const* d_in, const int* in_sizes, int n_in,
                              void* d_out, int out_size, void* d_ws, size_t ws_size,
                              hipStream_t stream) {
    const int* x     = (const int*)d_in[0];
    // d_in[1] = edge_index : unused by layer 0 (never read)
    const int* batch = (const int*)d_in[2];
    const float* B   = (const float*)d_in[3];
    const float* Pi  = (const float*)d_in[4];
    float* out       = (float*)d_out;
    float* T         = (float*)d_ws;                 // 512 floats
    int*   ranges    = (int*)((char*)d_ws + 4096);   // 2*n_graphs ints

    const int n_nodes  = in_sizes[0];
    const int n_graphs = out_size / NGEN;

    hipLaunchKernelGGL(cgmm_prep_kernel, dim3(256), dim3(256), 0, stream,
                       B, Pi, batch, T, ranges, n_nodes, n_graphs);
    hipLaunchKernelGGL(cgmm_graph_kernel,
                       dim3((n_graphs + GPB - 1) / GPB), dim3(512), 0, stream,
                       x, ranges, T, out, n_graphs);
}